// Round 14
// baseline (549.652 us; speedup 1.0000x reference)
//
#include <hip/hip_runtime.h>

// EntityLinker fused edge-MLP for MI355X (gfx950).
// Round 14: persistent blocks + register-resident weights.
//   R12 calibration: MfmaUtil 21.3% == 78cyc MFMA/(78+288cyc exposed) -- the
//   K-loop convoy waits full L2 latency per iteration and no scheme hides it
//   in-flight (compiler sinks reg prefetch; DMA depth too shallow). So remove
//   the loads: 512-thread blocks, each wave holds its N-slice of W1+W2 as 160
//   resident VGPRs loaded ONCE (R11 fragment-major packing); 256 persistent
//   blocks grid-stride over tiles. K-loops are pure ds_read+MFMA.
//   VGPR peak ~238 @ (512,2) => 2 waves/SIMD, 1 block/CU.

#define H 128

typedef __bf16 bf16x8 __attribute__((ext_vector_type(8)));
typedef float f32x4 __attribute__((ext_vector_type(4)));

__device__ __forceinline__ unsigned short f2bf(float f) {
    unsigned u = __builtin_bit_cast(unsigned, f);
    u += 0x7FFFu + ((u >> 16) & 1u);   // RNE
    return (unsigned short)(u >> 16);
}
__device__ __forceinline__ float bfhi(unsigned u) {
    return __builtin_bit_cast(float, u & 0xffff0000u);
}
__device__ __forceinline__ float bflo(unsigned u) {
    return __builtin_bit_cast(float, u << 16);
}
__device__ __forceinline__ unsigned pk2(float r0, float r1) {
    unsigned u0 = __builtin_bit_cast(unsigned, r0) + 0x8000u;
    unsigned u1 = __builtin_bit_cast(unsigned, r1) + 0x8000u;
    return __builtin_amdgcn_perm(u1, u0, 0x07060302u);
}
__device__ __forceinline__ unsigned comb(unsigned ua, unsigned ub, bool isdiff) {
    float a0 = bflo(ua), a1 = bfhi(ua);
    float b0 = bflo(ub), b1 = bfhi(ub);
    float r0 = isdiff ? fabsf(a0 - b0) : a0 * b0;
    float r1 = isdiff ? fabsf(a1 - b1) : a1 * b1;
    return pk2(r0, r1);
}
__device__ __forceinline__ unsigned short cvt1(float v) {
    unsigned u = __builtin_bit_cast(unsigned, v) + 0x8000u;
    return (unsigned short)(u >> 16);
}

__global__ void prep_node(const float* __restrict__ node, unsigned short* __restrict__ nbf) {
    int idx = blockIdx.x * 256 + threadIdx.x;
    const f32x4* p = (const f32x4*)(node) + idx;
    f32x4 v = *p;
    ushort4 w;
    w.x = f2bf(v.x); w.y = f2bf(v.y); w.z = f2bf(v.z); w.w = f2bf(v.w);
    *(ushort4*)(nbf + idx * 4) = w;
}

// Fragment-major pack of W1 [512][256]: W1P[(g_nt*16+ks)*512 + lane*8 + j]
//   = W1[k][row], row = g_nt*16+(lane&15), k = ks*32+(lane>>4)*8+j
__global__ void prep_w1(const float* __restrict__ W1, unsigned short* __restrict__ W1P) {
    int o = blockIdx.x * 256 + threadIdx.x;        // 131072
    int chunk = o >> 9;
    int g_nt = chunk >> 4;
    int ks = chunk & 15;
    int r = o & 511;
    int lane = r >> 3;
    int j = r & 7;
    int row = g_nt * 16 + (lane & 15);
    int k = ks * 32 + (lane >> 4) * 8 + j;
    W1P[o] = f2bf(W1[k * 256 + row]);
}

// Fragment-major pack of W2 [256][128]: W2P[(g_nt*8+ks)*512 + lane*8 + j]
__global__ void prep_w2(const float* __restrict__ W2, unsigned short* __restrict__ W2P) {
    int o = blockIdx.x * 256 + threadIdx.x;        // 32768
    int chunk = o >> 9;
    int g_nt = chunk >> 3;
    int ks = chunk & 7;
    int r = o & 511;
    int lane = r >> 3;
    int j = r & 7;
    int row = g_nt * 16 + (lane & 15);
    int k = ks * 32 + (lane >> 4) * 8 + j;
    W2P[o] = f2bf(W2[k * 128 + row]);
}

__launch_bounds__(512, 2)
__global__ void fused_mlp(const unsigned short* __restrict__ nbf,   // [N][128] bf16
                          const int* __restrict__ src,
                          const int* __restrict__ dst,
                          const unsigned short* __restrict__ W1P,  // packed
                          const float* __restrict__ b1,
                          const unsigned short* __restrict__ W2P,  // packed
                          const float* __restrict__ b2,
                          const float* __restrict__ W3,            // [128][2] f32
                          const float* __restrict__ b3,
                          float* __restrict__ out,                 // [E][2] f32
                          int E, int nTiles) {
    // sH: [64][268] bf16 (stride 536B: 16 lanes -> distinct-ish banks, worst
    // 2-way = free). hi cols 0..127 / hj cols 136..263; x1 overlays cols
    // 0..255; x2 overlays as [64][140].
    __shared__ __align__(16) unsigned short sH[64 * 268];    // 34304 B
    __shared__ __align__(16) float sW3[256];                 // [c][128]

    const int t = threadIdx.x;
    const int lane = t & 63;
    const int wv = t >> 6;         // 0..7
    const int quad = lane >> 4;
    const int lrow = lane & 15;
    const int nb = wv * 32;        // layer-1 N-slice (32 cols/wave)
    const int nb2 = wv * 16;       // layer-2 N-slice (16 cols/wave)

    if (t < 256) sW3[(t & 1) * 128 + (t >> 1)] = W3[t];   // [k][c] -> [c][k]

    // ---------------- One-time: resident weights + biases ----------------
    float b1v[2];
#pragma unroll
    for (int nt = 0; nt < 2; nt++) b1v[nt] = b1[nb + nt * 16 + lrow];
    const float b2v = b2[nb2 + lrow];

    bf16x8 bres1[16][2];           // 128 VGPRs: wave's L1 slice (cols nb..nb+31)
#pragma unroll
    for (int ks = 0; ks < 16; ks++)
#pragma unroll
        for (int j = 0; j < 2; j++)
            bres1[ks][j] = *(const bf16x8*)(W1P + ((2 * wv + j) * 16 + ks) * 512 + lane * 8);
    bf16x8 bres2[8];               // 32 VGPRs: wave's L2 slice (cols nb2..nb2+15)
#pragma unroll
    for (int ks = 0; ks < 8; ks++)
        bres2[ks] = *(const bf16x8*)(W2P + (wv * 8 + ks) * 512 + lane * 8);

    int aoff[4];
#pragma unroll
    for (int mt = 0; mt < 4; mt++) aoff[mt] = (mt * 16 + lrow) * 268 + quad * 8;

    // ======================= persistent tile loop =======================
    for (int tile = blockIdx.x; tile < nTiles; tile += gridDim.x) {
        const int e0 = tile * 64;
        __syncthreads();           // prev tile's phase-F reads done

        // ---- Phase A: gather hi/hj (bf16) -> LDS ----
        {
            int r = t >> 3;              // edge row 0..63
            int side = (t >> 2) & 1;     // 0=hi 1=hj
            int q = t & 3;               // 32-col quarter
            int e = e0 + r;
            int ec = e < E ? e : (E - 1);
            int nid = side ? dst[ec] : src[ec];
            const unsigned short* g = nbf + (long)nid * H + q * 32;
            unsigned short* rowp = sH + r * 268 + (side ? 136 : 0) + q * 32;
#pragma unroll
            for (int b = 0; b < 4; b++)
                *(uint4*)(rowp + b * 8) = *(const uint4*)(g + b * 8);
        }
        __syncthreads();

        // ---- Phase B: layer 1 (M=64, N=256 split 8 ways, K=512) ----
        f32x4 acc[4][2];
#pragma unroll
        for (int mt = 0; mt < 4; mt++)
#pragma unroll
            for (int nt = 0; nt < 2; nt++)
                acc[mt][nt] = (f32x4){0.f, 0.f, 0.f, 0.f};

        // K-half 1: k 0..255 (A = hi | hj) -- pure LDS + MFMA
#pragma unroll
        for (int ks = 0; ks < 8; ks++) {
            const int ao = (ks < 4) ? ks * 32 : 136 + (ks - 4) * 32;
            bf16x8 av[4];
#pragma unroll
            for (int mt = 0; mt < 4; mt++) av[mt] = *(const bf16x8*)(sH + aoff[mt] + ao);
#pragma unroll
            for (int mt = 0; mt < 4; mt++)
#pragma unroll
                for (int nt = 0; nt < 2; nt++)
                    acc[mt][nt] = __builtin_amdgcn_mfma_f32_16x16x32_bf16(av[mt], bres1[ks][nt], acc[mt][nt], 0, 0, 0);
        }
        __syncthreads();           // half-1 reads of hi/hj done

        // ---- Staging: diff -> P (cols 0..127), prod -> Q (136..263), in place --
        {
            int r = t >> 3;
            int c0 = (t & 7) * 16;
            unsigned short* rowp = sH + r * 268;
#pragma unroll
            for (int j = 0; j < 2; j++) {
                uint4 ua = *(const uint4*)(rowp + c0 + j * 8);
                uint4 ub = *(const uint4*)(rowp + 136 + c0 + j * 8);
                uint4 dd, pp;
                dd.x = comb(ua.x, ub.x, true);  dd.y = comb(ua.y, ub.y, true);
                dd.z = comb(ua.z, ub.z, true);  dd.w = comb(ua.w, ub.w, true);
                pp.x = comb(ua.x, ub.x, false); pp.y = comb(ua.y, ub.y, false);
                pp.z = comb(ua.z, ub.z, false); pp.w = comb(ua.w, ub.w, false);
                *(uint4*)(rowp + c0 + j * 8)       = dd;
                *(uint4*)(rowp + 136 + c0 + j * 8) = pp;
            }
        }
        __syncthreads();           // diff/prod staged

        // K-half 2: k 256..511 (A = diff | prod, same addressing)
#pragma unroll
        for (int ks = 0; ks < 8; ks++) {
            const int ao = (ks < 4) ? ks * 32 : 136 + (ks - 4) * 32;
            bf16x8 av[4];
#pragma unroll
            for (int mt = 0; mt < 4; mt++) av[mt] = *(const bf16x8*)(sH + aoff[mt] + ao);
#pragma unroll
            for (int mt = 0; mt < 4; mt++)
#pragma unroll
                for (int nt = 0; nt < 2; nt++)
                    acc[mt][nt] = __builtin_amdgcn_mfma_f32_16x16x32_bf16(av[mt], bres1[ks + 8][nt], acc[mt][nt], 0, 0, 0);
        }
        __syncthreads();           // all layer-1 reads of sH done

        // ---- Phase C: relu+bias -> x1 bf16 (overlay sH, cols 0..255) ----
        unsigned short* sx1 = sH;
#pragma unroll
        for (int mt = 0; mt < 4; mt++)
#pragma unroll
            for (int nt = 0; nt < 2; nt++)
#pragma unroll
                for (int i = 0; i < 4; i++) {
                    int row = mt * 16 + quad * 4 + i;   // C/D: row = quad*4 + reg
                    int col = nb + nt * 16 + lrow;      //      col = lane&15
                    float v = acc[mt][nt][i] + b1v[nt];
                    v = v > 0.f ? v : 0.f;
                    sx1[row * 268 + col] = cvt1(v);
                }
        __syncthreads();           // x1 complete

        // ---- Phase D: layer 2 (M=64, N=128 split 8 ways, K=256) ----
        f32x4 acc2[4];
#pragma unroll
        for (int mt = 0; mt < 4; mt++) acc2[mt] = (f32x4){0.f, 0.f, 0.f, 0.f};
#pragma unroll
        for (int ks = 0; ks < 8; ks++) {
            bf16x8 av2[4];
#pragma unroll
            for (int mt = 0; mt < 4; mt++) av2[mt] = *(const bf16x8*)(sx1 + aoff[mt] + ks * 32);
#pragma unroll
            for (int mt = 0; mt < 4; mt++)
                acc2[mt] = __builtin_amdgcn_mfma_f32_16x16x32_bf16(av2[mt], bres2[ks], acc2[mt], 0, 0, 0);
        }
        __syncthreads();           // layer-2 reads of x1 done

        // ---- Phase E: relu+bias -> x2 bf16 (overlay, [64][140]) ----
        unsigned short* sx2 = sH;
#pragma unroll
        for (int mt = 0; mt < 4; mt++)
#pragma unroll
            for (int i = 0; i < 4; i++) {
                int row = mt * 16 + quad * 4 + i;
                int col = nb2 + lrow;
                float v = acc2[mt][i] + b2v;
                v = v > 0.f ? v : 0.f;
                sx2[row * 140 + col] = cvt1(v);
            }
        __syncthreads();

        // ---- Phase F: layer 3 (N=2), 4 threads per (row,class) ----
        {
            int r = t >> 3;            // edge row 0..63
            int c = (t >> 2) & 1;      // class
            int h = t & 3;             // K-quarter
            const unsigned short* xr = sx2 + r * 140 + h * 32;
            const float* w3c = sW3 + c * 128 + h * 32;
            float s = 0.f;
#pragma unroll
            for (int j = 0; j < 4; j++) {
                uint4 v = *(const uint4*)(xr + j * 8);
                const float* w = w3c + j * 8;
                s += bflo(v.x) * w[0] + bfhi(v.x) * w[1]
                   + bflo(v.y) * w[2] + bfhi(v.y) * w[3]
                   + bflo(v.z) * w[4] + bfhi(v.z) * w[5]
                   + bflo(v.w) * w[6] + bfhi(v.w) * w[7];
            }
            s += __shfl_xor(s, 1);     // combine K-quarters (lanes h^1, h^2:
            s += __shfl_xor(s, 2);     //  same 4-lane group, same wave)
            int e = e0 + r;
            if (h == 0 && e < E) out[e * 2 + c] = s + b3[c];
        }
    }
}

extern "C" void kernel_launch(void* const* d_in, const int* in_sizes, int n_in,
                              void* d_out, int out_size, void* d_ws, size_t ws_size,
                              hipStream_t stream) {
    const float* node = (const float*)d_in[0];
    const int* src    = (const int*)d_in[1];
    const int* dst    = (const int*)d_in[2];
    const float* W1   = (const float*)d_in[3];
    const float* b1   = (const float*)d_in[4];
    const float* W2   = (const float*)d_in[5];
    const float* b2   = (const float*)d_in[6];
    const float* W3   = (const float*)d_in[7];
    const float* b3   = (const float*)d_in[8];
    float* out = (float*)d_out;
    const int NN = in_sizes[0] / H;                    // 50000 nodes
    const int E = in_sizes[1];

    unsigned short* W1P = (unsigned short*)d_ws;       // packed W1, 256 KiB
    unsigned short* W2P = W1P + 512 * 256;             // packed W2, 64 KiB
    unsigned short* NBF = W2P + 256 * 128;             // [N][128] bf16, 12.8 MB

    hipLaunchKernelGGL(prep_node, dim3((NN * H / 4 + 255) / 256), dim3(256), 0, stream, node, NBF);
    hipLaunchKernelGGL(prep_w1, dim3(512), dim3(256), 0, stream, W1, W1P);
    hipLaunchKernelGGL(prep_w2, dim3(128), dim3(256), 0, stream, W2, W2P);
    const int nTiles = (E + 63) / 64;                  // 7813
    hipLaunchKernelGGL(fused_mlp, dim3(256), dim3(512), 0, stream,
                       NBF, src, dst, W1P, b1, W2P, b2, W3, b3, out, E, nTiles);
}

// Round 16
// 382.596 us; speedup vs baseline: 1.4366x; 1.4366x over previous
//
#include <hip/hip_runtime.h>

// EntityLinker fused edge-MLP for MI355X (gfx950).
// Round 16: R15 (R12-structure @ 4 blocks/CU) with phase-A coverage fix:
//   the (row, side, 64-col-half) split needs 8 uint4 copies per thread, not 4
//   (R15 left half the tile poisoned -> NaN).
//   - __launch_bounds__(256,4): R12 body = 60 arch VGPR + 64 AGPR acc = 124
//     unified <= 128 budget. LDS 35.3 KB x 4 = 141 KB <= 160.
//   - Keeps: bf16 node cache, fragment-major packed weights, staged in-place
//     diff/prod, rolled K-loops, cheap cvt.

#define H 128

typedef __bf16 bf16x8 __attribute__((ext_vector_type(8)));
typedef float f32x4 __attribute__((ext_vector_type(4)));

__device__ __forceinline__ unsigned short f2bf(float f) {
    unsigned u = __builtin_bit_cast(unsigned, f);
    u += 0x7FFFu + ((u >> 16) & 1u);   // RNE
    return (unsigned short)(u >> 16);
}
__device__ __forceinline__ float bfhi(unsigned u) {
    return __builtin_bit_cast(float, u & 0xffff0000u);
}
__device__ __forceinline__ float bflo(unsigned u) {
    return __builtin_bit_cast(float, u << 16);
}
__device__ __forceinline__ unsigned pk2(float r0, float r1) {
    unsigned u0 = __builtin_bit_cast(unsigned, r0) + 0x8000u;
    unsigned u1 = __builtin_bit_cast(unsigned, r1) + 0x8000u;
    return __builtin_amdgcn_perm(u1, u0, 0x07060302u);
}
__device__ __forceinline__ unsigned comb(unsigned ua, unsigned ub, bool isdiff) {
    float a0 = bflo(ua), a1 = bfhi(ua);
    float b0 = bflo(ub), b1 = bfhi(ub);
    float r0 = isdiff ? fabsf(a0 - b0) : a0 * b0;
    float r1 = isdiff ? fabsf(a1 - b1) : a1 * b1;
    return pk2(r0, r1);
}
__device__ __forceinline__ unsigned short cvt1(float v) {
    unsigned u = __builtin_bit_cast(unsigned, v) + 0x8000u;
    return (unsigned short)(u >> 16);
}

__global__ void prep_node(const float* __restrict__ node, unsigned short* __restrict__ nbf) {
    int idx = blockIdx.x * 256 + threadIdx.x;
    const f32x4* p = (const f32x4*)(node) + idx;
    f32x4 v = *p;
    ushort4 w;
    w.x = f2bf(v.x); w.y = f2bf(v.y); w.z = f2bf(v.z); w.w = f2bf(v.w);
    *(ushort4*)(nbf + idx * 4) = w;
}

// Fragment-major pack of W1 [512][256]: W1P[(g_nt*16+ks)*512 + lane*8 + j]
//   = W1[k][row], row = g_nt*16+(lane&15), k = ks*32+(lane>>4)*8+j
__global__ void prep_w1(const float* __restrict__ W1, unsigned short* __restrict__ W1P) {
    int o = blockIdx.x * 256 + threadIdx.x;        // 131072
    int chunk = o >> 9;
    int g_nt = chunk >> 4;
    int ks = chunk & 15;
    int r = o & 511;
    int lane = r >> 3;
    int j = r & 7;
    int row = g_nt * 16 + (lane & 15);
    int k = ks * 32 + (lane >> 4) * 8 + j;
    W1P[o] = f2bf(W1[k * 256 + row]);
}

// Fragment-major pack of W2 [256][128]: W2P[(g_nt*8+ks)*512 + lane*8 + j]
__global__ void prep_w2(const float* __restrict__ W2, unsigned short* __restrict__ W2P) {
    int o = blockIdx.x * 256 + threadIdx.x;        // 32768
    int chunk = o >> 9;
    int g_nt = chunk >> 3;
    int ks = chunk & 7;
    int r = o & 511;
    int lane = r >> 3;
    int j = r & 7;
    int row = g_nt * 16 + (lane & 15);
    int k = ks * 32 + (lane >> 4) * 8 + j;
    W2P[o] = f2bf(W2[k * 128 + row]);
}

__launch_bounds__(256, 4)
__global__ void fused_mlp(const unsigned short* __restrict__ nbf,   // [N][128] bf16
                          const int* __restrict__ src,
                          const int* __restrict__ dst,
                          const unsigned short* __restrict__ W1P,  // packed
                          const float* __restrict__ b1,
                          const unsigned short* __restrict__ W2P,  // packed
                          const float* __restrict__ b2,
                          const float* __restrict__ W3,            // [128][2] f32
                          const float* __restrict__ b3,
                          float* __restrict__ out,                 // [E][2] f32
                          int E) {
    // sH: [64][268] bf16. Region P (cols 0..127): hi -> diff.
    //                     Region Q (cols 136..263): hj -> prod.
    // Overlays: x1 [64][268] cols 0..255; x2 [64][140].
    __shared__ __align__(16) unsigned short sH[64 * 268];    // 34304 B
    __shared__ __align__(16) float sW3[256];                 // [c][128]

    const int t = threadIdx.x;
    const int e0 = blockIdx.x * 64;

    const int lane = t & 63;
    const int wv = t >> 6;
    const int quad = lane >> 4;
    const int lrow = lane & 15;
    const int nb = wv * 64;        // layer-1 N-slice
    const int nb2 = wv * 32;       // layer-2 N-slice

    // ---------------- Phase A: gather hi/hj (bf16) -> LDS, one side/thread ------
    {
        int r = t >> 2;            // edge row 0..63
        int side = (t >> 1) & 1;   // 0 = hi(src), 1 = hj(dst)
        int q = t & 1;             // 64-col half
        int e = e0 + r;
        int ec = e < E ? e : (E - 1);
        int nid = side ? dst[ec] : src[ec];
        const unsigned short* g = nbf + (long)nid * H + q * 64;
        unsigned short* rowp = sH + r * 268 + (side ? 136 : 0) + q * 64;
#pragma unroll
        for (int b = 0; b < 8; b++)            // 8 x uint4 = 64 shorts (fix)
            *(uint4*)(rowp + b * 8) = *(const uint4*)(g + b * 8);
        sW3[(t & 1) * 128 + (t >> 1)] = W3[t];   // [k][c] -> [c][k]
    }
    __syncthreads();               // hi/hj visible

    // ---------------- Phase B: layer 1 (M=64, N=256, K=512) ----------------
    const unsigned short* w1p[4];
#pragma unroll
    for (int nt = 0; nt < 4; nt++) w1p[nt] = W1P + (wv * 4 + nt) * 16 * 512 + lane * 8;

    f32x4 acc[4][4];
#pragma unroll
    for (int mt = 0; mt < 4; mt++)
#pragma unroll
        for (int nt = 0; nt < 4; nt++)
            acc[mt][nt] = (f32x4){0.f, 0.f, 0.f, 0.f};

    int aoff[4];
#pragma unroll
    for (int mt = 0; mt < 4; mt++) aoff[mt] = (mt * 16 + lrow) * 268 + quad * 8;

    // K-half 1: k 0..255  (A = hi | hj, as stored)
#pragma unroll 1
    for (int ks = 0; ks < 8; ks++) {
        const int ao = (ks < 4) ? ks * 32 : 136 + (ks - 4) * 32;
        bf16x8 bv[4], av[4];
#pragma unroll
        for (int nt = 0; nt < 4; nt++) bv[nt] = *(const bf16x8*)(w1p[nt] + ks * 512);
#pragma unroll
        for (int mt = 0; mt < 4; mt++) av[mt] = *(const bf16x8*)(sH + aoff[mt] + ao);
#pragma unroll
        for (int mt = 0; mt < 4; mt++)
#pragma unroll
            for (int nt = 0; nt < 4; nt++)
                acc[mt][nt] = __builtin_amdgcn_mfma_f32_16x16x32_bf16(av[mt], bv[nt], acc[mt][nt], 0, 0, 0);
    }

    __syncthreads();               // half-1 reads of hi/hj complete

    // ------------- Staging: diff -> region P, prod -> region Q (in place) -------
    {
        int r = t >> 2;
        int c0 = (t & 3) * 32;
        unsigned short* rowp = sH + r * 268;
#pragma unroll
        for (int j = 0; j < 4; j++) {
            uint4 ua = *(const uint4*)(rowp + c0 + j * 8);
            uint4 ub = *(const uint4*)(rowp + 136 + c0 + j * 8);
            uint4 dd, pp;
            dd.x = comb(ua.x, ub.x, true);  dd.y = comb(ua.y, ub.y, true);
            dd.z = comb(ua.z, ub.z, true);  dd.w = comb(ua.w, ub.w, true);
            pp.x = comb(ua.x, ub.x, false); pp.y = comb(ua.y, ub.y, false);
            pp.z = comb(ua.z, ub.z, false); pp.w = comb(ua.w, ub.w, false);
            *(uint4*)(rowp + c0 + j * 8)       = dd;
            *(uint4*)(rowp + 136 + c0 + j * 8) = pp;
        }
    }
    __syncthreads();               // diff/prod staged

    // K-half 2: k 256..511 (A = diff | prod, same addressing)
#pragma unroll 1
    for (int ks = 0; ks < 8; ks++) {
        const int ao = (ks < 4) ? ks * 32 : 136 + (ks - 4) * 32;
        bf16x8 bv[4], av[4];
#pragma unroll
        for (int nt = 0; nt < 4; nt++) bv[nt] = *(const bf16x8*)(w1p[nt] + (ks + 8) * 512);
#pragma unroll
        for (int mt = 0; mt < 4; mt++) av[mt] = *(const bf16x8*)(sH + aoff[mt] + ao);
#pragma unroll
        for (int mt = 0; mt < 4; mt++)
#pragma unroll
            for (int nt = 0; nt < 4; nt++)
                acc[mt][nt] = __builtin_amdgcn_mfma_f32_16x16x32_bf16(av[mt], bv[nt], acc[mt][nt], 0, 0, 0);
    }

    // ---------------- Phase C: relu+bias -> x1 bf16 (overlay sH) ----------------
    float b1v[4];
#pragma unroll
    for (int nt = 0; nt < 4; nt++) b1v[nt] = b1[nb + nt * 16 + lrow];

    __syncthreads();               // all layer-1 reads of sH done
    unsigned short* sx1 = sH;      // [64][268], cols 0..255
#pragma unroll
    for (int mt = 0; mt < 4; mt++)
#pragma unroll
        for (int nt = 0; nt < 4; nt++)
#pragma unroll
            for (int i = 0; i < 4; i++) {
                int row = mt * 16 + quad * 4 + i;    // C/D: row = quad*4 + reg
                int col = nb + nt * 16 + lrow;       //      col = lane&15
                float v = acc[mt][nt][i] + b1v[nt];
                v = v > 0.f ? v : 0.f;
                sx1[row * 268 + col] = cvt1(v);
            }
    __syncthreads();               // x1 complete

    // ---------------- Phase D: layer 2 (M=64, N=128, K=256) ----------------
    const unsigned short* w2p[2];
#pragma unroll
    for (int nt = 0; nt < 2; nt++) w2p[nt] = W2P + (wv * 2 + nt) * 8 * 512 + lane * 8;

    f32x4 acc2[4][2];
#pragma unroll
    for (int mt = 0; mt < 4; mt++)
#pragma unroll
        for (int nt = 0; nt < 2; nt++)
            acc2[mt][nt] = (f32x4){0.f, 0.f, 0.f, 0.f};

#pragma unroll 1
    for (int ks = 0; ks < 8; ks++) {
        bf16x8 bv2[2], av2[4];
#pragma unroll
        for (int nt = 0; nt < 2; nt++) bv2[nt] = *(const bf16x8*)(w2p[nt] + ks * 512);
#pragma unroll
        for (int mt = 0; mt < 4; mt++) av2[mt] = *(const bf16x8*)(sx1 + aoff[mt] + ks * 32);
#pragma unroll
        for (int mt = 0; mt < 4; mt++)
#pragma unroll
            for (int nt = 0; nt < 2; nt++)
                acc2[mt][nt] = __builtin_amdgcn_mfma_f32_16x16x32_bf16(av2[mt], bv2[nt], acc2[mt][nt], 0, 0, 0);
    }

    // ---------------- Phase E: relu+bias -> x2 bf16 (overlay) ----------------
    float b2v[2];
#pragma unroll
    for (int nt = 0; nt < 2; nt++) b2v[nt] = b2[nb2 + nt * 16 + lrow];

    __syncthreads();               // all layer-2 reads of x1 done
    unsigned short* sx2 = sH;      // [64][140] (70 dw stride, gcd 2 -> free)
#pragma unroll
    for (int mt = 0; mt < 4; mt++)
#pragma unroll
        for (int nt = 0; nt < 2; nt++)
#pragma unroll
            for (int i = 0; i < 4; i++) {
                int row = mt * 16 + quad * 4 + i;
                int col = nb2 + nt * 16 + lrow;
                float v = acc2[mt][nt][i] + b2v[nt];
                v = v > 0.f ? v : 0.f;
                sx2[row * 140 + col] = cvt1(v);
            }
    __syncthreads();

    // ---------------- Phase F: layer 3 (N=2), half-dots + shfl ----------------
    {
        int r = t >> 2;            // edge row 0..63
        int c = t & 1;             // class
        int h = (t >> 1) & 1;      // K-half
        const unsigned short* xr = sx2 + r * 140 + h * 64;
        const float* w3c = sW3 + c * 128 + h * 64;
        float s = 0.f;
#pragma unroll
        for (int j = 0; j < 8; j++) {
            uint4 v = *(const uint4*)(xr + j * 8);
            const float* w = w3c + j * 8;
            s += bflo(v.x) * w[0] + bfhi(v.x) * w[1]
               + bflo(v.y) * w[2] + bfhi(v.y) * w[3]
               + bflo(v.z) * w[4] + bfhi(v.z) * w[5]
               + bflo(v.w) * w[6] + bfhi(v.w) * w[7];
        }
        s += __shfl_xor(s, 2);     // combine K-halves
        int e = e0 + r;
        if (h == 0 && e < E) out[e * 2 + c] = s + b3[c];
    }
}

extern "C" void kernel_launch(void* const* d_in, const int* in_sizes, int n_in,
                              void* d_out, int out_size, void* d_ws, size_t ws_size,
                              hipStream_t stream) {
    const float* node = (const float*)d_in[0];
    const int* src    = (const int*)d_in[1];
    const int* dst    = (const int*)d_in[2];
    const float* W1   = (const float*)d_in[3];
    const float* b1   = (const float*)d_in[4];
    const float* W2   = (const float*)d_in[5];
    const float* b2   = (const float*)d_in[6];
    const float* W3   = (const float*)d_in[7];
    const float* b3   = (const float*)d_in[8];
    float* out = (float*)d_out;
    const int NN = in_sizes[0] / H;                    // 50000 nodes
    const int E = in_sizes[1];

    unsigned short* W1P = (unsigned short*)d_ws;       // packed W1, 256 KiB
    unsigned short* W2P = W1P + 512 * 256;             // packed W2, 64 KiB
    unsigned short* NBF = W2P + 256 * 128;             // [N][128] bf16, 12.8 MB

    hipLaunchKernelGGL(prep_node, dim3((NN * H / 4 + 255) / 256), dim3(256), 0, stream, node, NBF);
    hipLaunchKernelGGL(prep_w1, dim3(512), dim3(256), 0, stream, W1, W1P);
    hipLaunchKernelGGL(prep_w2, dim3(128), dim3(256), 0, stream, W2, W2P);
    const int nblk = (E + 63) / 64;
    hipLaunchKernelGGL(fused_mlp, dim3(nblk), dim3(256), 0, stream,
                       NBF, src, dst, W1P, b1, W2P, b2, W3, b3, out, E);
}